// Round 5
// baseline (72.622 us; speedup 1.0000x reference)
//
#include <hip/hip_runtime.h>

// entmax_bisect, alpha=1.5, rows of N=2048 fp32. One wave64 per row-task,
// RPW=4 rows per wave, software-pipelined: next row's global loads are issued
// as soon as the current row's raw registers are consumed, so HBM/L3 traffic
// issues continuously instead of in per-row bursts (round-4 showed ~3.6 TB/s
// effective vs 6.3 achievable with bursty loads).
//
// Math (validated rounds 2-4, absmax ~1e-3 vs 2e-2 threshold):
//   v = 0.5*x - 0.5*max  => max element -> exactly 0; bracket (lo,hi)=(-1,0);
//   am1=0.5 => power(d,1/am1)=d*d. All midpoints and tau lie in (-1,0], so
//   elements with v <= -1 contribute exactly 0 everywhere -> compact
//   candidates (v > -1, ~140/2048 for N(0,1)) into <=12 LDS slots per lane.
//   P1: K1=6 bisect iters on candidates (bracket 2^-6), s(lo) > 1 >= s(hi).
//   P2: aggregates (n,S1,S2) over certain support {v > hi} centered at hi;
//       boundary elements in (lo,hi] compacted (<=8).
//   P3: sort boundary desc, greedy prefix-accept (s monotone), closed-form
//       tau = hi + (S1 - sqrt(S1^2 - n(S2-1)))/n  (== 50-iter bisection limit
//       to 2^-44 << fp32 rounding).
//   Fallbacks (exact): >12 candidates in a lane -> 50 full-pass iterations on
//   v[32]; >8 boundary -> 44 more bisect iterations on candidates.

typedef float f32x4 __attribute__((ext_vector_type(4)));

constexpr int N = 2048;
constexpr int PER_LANE = N / 64;      // 32
constexpr int WPB = 4;                // waves per 256-thread block
constexpr int RPW = 4;                // rows per wave (software pipeline)
constexpr int CAPL = 12;              // candidate capacity per lane
constexpr int BMAX = 8;
constexpr int K1 = 6;
constexpr int TOTAL_ITER = 50;

__device__ __forceinline__ float wave_sum(float s) {
    #pragma unroll
    for (int off = 32; off >= 1; off >>= 1)
        s += __shfl_xor(s, off, 64);
    return s;
}
__device__ __forceinline__ float wave_max(float m) {
    #pragma unroll
    for (int off = 32; off >= 1; off >>= 1)
        m = fmaxf(m, __shfl_xor(m, off, 64));
    return m;
}

// Process one row given its transformed values v[32] (v = 0.5*x - 0.5*max).
// Writes p to outr. LDS slices are wave-private (same-wave DS ordering only).
__device__ __forceinline__ void solve_and_store(
        float (&v)[PER_LANE], f32x4* __restrict__ outr, int lane,
        float (&cand)[CAPL][64], float (&bnd)[BMAX], int* cntp) {

    // ---- Candidate compaction: v > -1 into per-lane LDS slots ----
    #pragma unroll
    for (int k = 0; k < CAPL; ++k) cand[k][lane] = -1e30f;
    if (lane < BMAX) bnd[lane] = -1e30f;
    if (lane == 0)   *cntp = 0;

    int j = 0;
    #pragma unroll
    for (int i = 0; i < PER_LANE; ++i) {
        const bool c = v[i] > -1.0f;
        const int  slot = (j < CAPL - 1) ? j : (CAPL - 1);  // clamp; ovf caught
        if (c) cand[slot][lane] = v[i];
        j += c ? 1 : 0;
    }

    float tau, ssum;
    if (!__any(j > CAPL)) {
        float cd[CAPL];
        #pragma unroll
        for (int k = 0; k < CAPL; ++k) cd[k] = cand[k][lane];

        float lo = -1.0f, hi = 0.0f;
        for (int it = 0; it < K1; ++it) {
            const float mid = 0.5f * (lo + hi);
            float sa = 0.f, sb = 0.f;
            #pragma unroll
            for (int k = 0; k < CAPL; k += 2) {
                float d0 = fmaxf(cd[k]   - mid, 0.f);
                float d1 = fmaxf(cd[k+1] - mid, 0.f);
                sa = fmaf(d0, d0, sa);
                sb = fmaf(d1, d1, sb);
            }
            float s = wave_sum(sa + sb);
            if (s > 1.0f) lo = mid; else hi = mid;
        }

        const float cth = hi, lof = lo;
        float nA = 0.f, S1 = 0.f, S2 = 0.f;
        #pragma unroll
        for (int k = 0; k < CAPL; ++k) {
            float u  = cd[k] - cth;
            float um = fmaxf(u, 0.f);
            nA += (u > 0.f) ? 1.0f : 0.0f;
            S1 += um;
            S2  = fmaf(um, um, S2);
            if (u <= 0.f && cd[k] > lof) {          // boundary: rare
                int t = atomicAdd(cntp, 1);
                if (t < BMAX) bnd[t] = cd[k];
            }
        }
        nA = wave_sum(nA); S1 = wave_sum(S1); S2 = wave_sum(S2);

        const int cnt = *cntp;                      // wave-uniform
        if (cnt <= BMAX) {
            float b0 = bnd[0], b1 = bnd[1], b2 = bnd[2], b3 = bnd[3];
            float b4 = bnd[4], b5 = bnd[5], b6 = bnd[6], b7 = bnd[7];
            // Sort descending (Batcher odd-even merge, 19 CEs); sentinels sink.
            #define CE(a, b) { float _t = fmaxf(a, b); b = fminf(a, b); a = _t; }
            CE(b0,b1) CE(b2,b3) CE(b4,b5) CE(b6,b7)
            CE(b0,b2) CE(b1,b3) CE(b4,b6) CE(b5,b7)
            CE(b1,b2) CE(b5,b6)
            CE(b0,b4) CE(b1,b5) CE(b2,b6) CE(b3,b7)
            CE(b2,b4) CE(b3,b5)
            CE(b1,b2) CE(b3,b4) CE(b5,b6)
            #undef CE
            // Greedy prefix-accept (sentinels: s=+inf => reject).
            float nk = nA, S1k = S1, S2k = S2;
            #define STEP(bk) {                                              \
                float t_  = bk - cth;                                       \
                float sc_ = fmaf(t_, fmaf(nk, t_, -2.0f * S1k), S2k);       \
                bool  ac_ = sc_ < 1.0f;                                     \
                float ta_ = ac_ ? t_ : 0.0f;                                \
                nk  += ac_ ? 1.0f : 0.0f;                                   \
                S1k += ta_;                                                 \
                S2k  = fmaf(ta_, ta_, S2k); }
            STEP(b0) STEP(b1) STEP(b2) STEP(b3)
            STEP(b4) STEP(b5) STEP(b6) STEP(b7)
            #undef STEP
            float disc = fmaxf(fmaf(S1k, S1k, -nk * (S2k - 1.0f)), 0.0f);
            tau = cth + (S1k - sqrtf(disc)) / nk;
        } else {
            // Boundary overflow: finish the reference's remaining iterations
            // on the compacted set (non-candidates contribute exactly 0).
            for (int it = 0; it < TOTAL_ITER - K1; ++it) {
                const float mid = 0.5f * (lo + hi);
                float sa = 0.f, sb = 0.f;
                #pragma unroll
                for (int k = 0; k < CAPL; k += 2) {
                    float d0 = fmaxf(cd[k]   - mid, 0.f);
                    float d1 = fmaxf(cd[k+1] - mid, 0.f);
                    sa = fmaf(d0, d0, sa);
                    sb = fmaf(d1, d1, sb);
                }
                float s = wave_sum(sa + sb);
                if (s > 1.0f) lo = mid; else hi = mid;
            }
            tau = 0.5f * (lo + hi);
        }

        // Normalizing sum from candidates (non-candidates are exactly 0).
        float sa = 0.f, sb = 0.f;
        #pragma unroll
        for (int k = 0; k < CAPL; k += 2) {
            float d0 = fmaxf(cd[k]   - tau, 0.f);
            float d1 = fmaxf(cd[k+1] - tau, 0.f);
            sa = fmaf(d0, d0, sa);
            sb = fmaf(d1, d1, sb);
        }
        ssum = wave_sum(sa + sb);
    } else {
        // ---- Lane-overflow fallback: full 50-iteration bisection on v ----
        float lo = -1.0f, hi = 0.0f;
        for (int it = 0; it < TOTAL_ITER; ++it) {
            const float mid = 0.5f * (lo + hi);
            float s0 = 0.f, s1_ = 0.f, s2_ = 0.f, s3_ = 0.f;
            #pragma unroll
            for (int i = 0; i < PER_LANE; i += 4) {
                float d0 = fmaxf(v[i+0] - mid, 0.f);
                float d1 = fmaxf(v[i+1] - mid, 0.f);
                float d2 = fmaxf(v[i+2] - mid, 0.f);
                float d3 = fmaxf(v[i+3] - mid, 0.f);
                s0 = fmaf(d0, d0, s0); s1_ = fmaf(d1, d1, s1_);
                s2_ = fmaf(d2, d2, s2_); s3_ = fmaf(d3, d3, s3_);
            }
            float s = wave_sum((s0 + s1_) + (s2_ + s3_));
            if (s > 1.0f) lo = mid; else hi = mid;
        }
        tau = 0.5f * (lo + hi);
        float s0 = 0.f;
        #pragma unroll
        for (int i = 0; i < PER_LANE; ++i) {
            float d = fmaxf(v[i] - tau, 0.f);
            s0 = fmaf(d, d, s0);
        }
        ssum = wave_sum(s0);
    }

    // ---- Epilogue: p = max(v - tau, 0)^2 * inv, non-temporal stores ----
    const float inv = 1.0f / fmaxf(ssum, 1e-12f);
    #pragma unroll
    for (int c = 0; c < PER_LANE / 4; ++c) {
        float d0 = fmaxf(v[4*c+0] - tau, 0.f);
        float d1 = fmaxf(v[4*c+1] - tau, 0.f);
        float d2 = fmaxf(v[4*c+2] - tau, 0.f);
        float d3 = fmaxf(v[4*c+3] - tau, 0.f);
        f32x4 t;
        t.x = (d0 * d0) * inv;
        t.y = (d1 * d1) * inv;
        t.z = (d2 * d2) * inv;
        t.w = (d3 * d3) * inv;
        __builtin_nontemporal_store(t, &outr[lane + 64 * c]);
    }
}

__global__ __launch_bounds__(256, 4)
void entmax15_kernel(const float* __restrict__ x,
                     float* __restrict__ out, int rows) {
    __shared__ float s_cand[WPB][CAPL][64];   // slot-major: conflict-free
    __shared__ float s_bnd[WPB][BMAX];
    __shared__ int   s_cnt[WPB];

    const int wave = threadIdx.x >> 6;
    const int lane = threadIdx.x & 63;
    const int gw   = blockIdx.x * WPB + wave;     // global wave id
    const int nwaves = gridDim.x * WPB;           // = rows / RPW

    // Prefetch row 0 for this wave.
    f32x4 pf[8];
    {
        const f32x4* xr = reinterpret_cast<const f32x4*>(x + (size_t)gw * N);
        #pragma unroll
        for (int c = 0; c < 8; ++c) pf[c] = xr[lane + 64 * c];
    }

    #pragma unroll
    for (int k = 0; k < RPW; ++k) {
        const int row = gw + k * nwaves;
        if (row >= rows) return;

        // Row max straight from the raw prefetch registers.
        float m = fmaxf(fmaxf(pf[0].x, pf[0].y), fmaxf(pf[0].z, pf[0].w));
        #pragma unroll
        for (int c = 1; c < 8; ++c)
            m = fmaxf(m, fmaxf(fmaxf(pf[c].x, pf[c].y), fmaxf(pf[c].z, pf[c].w)));
        m = wave_max(m);

        // v = 0.5*x - 0.5*m (argmax -> exactly 0). pf becomes dead here.
        const float nhm = -0.5f * m;
        float v[PER_LANE];
        #pragma unroll
        for (int c = 0; c < 8; ++c) {
            v[4*c+0] = fmaf(0.5f, pf[c].x, nhm);
            v[4*c+1] = fmaf(0.5f, pf[c].y, nhm);
            v[4*c+2] = fmaf(0.5f, pf[c].z, nhm);
            v[4*c+3] = fmaf(0.5f, pf[c].w, nhm);
        }

        // Issue next row's loads NOW: their latency hides under the ~1 us of
        // bisection + epilogue below (continuous memory issue across waves).
        if (k + 1 < RPW) {
            const int nrow = gw + (k + 1) * nwaves;
            if (nrow < rows) {
                const f32x4* xr = reinterpret_cast<const f32x4*>(x + (size_t)nrow * N);
                #pragma unroll
                for (int c = 0; c < 8; ++c) pf[c] = xr[lane + 64 * c];
            }
        }

        f32x4* outr = reinterpret_cast<f32x4*>(out + (size_t)row * N);
        solve_and_store(v, outr, lane, s_cand[wave], s_bnd[wave], &s_cnt[wave]);
    }
}

extern "C" void kernel_launch(void* const* d_in, const int* in_sizes, int n_in,
                              void* d_out, int out_size, void* d_ws, size_t ws_size,
                              hipStream_t stream) {
    const float* x = (const float*)d_in[0];
    float* out = (float*)d_out;
    const int rows = in_sizes[0] / N;                       // 16384
    const int nwaves = (rows + RPW - 1) / RPW;              // 4096
    const int blocks = (nwaves + WPB - 1) / WPB;            // 1024
    entmax15_kernel<<<blocks, 64 * WPB, 0, stream>>>(x, out, rows);
}